// Round 6
// baseline (525.717 us; speedup 1.0000x reference)
//
#include <hip/hip_runtime.h>

#define N_NODES 100000
#define N_EDGES 3200000
#define N_GRAPHS 512
#define IN_CH 50
#define HID 256
#define NB 391          // buckets of 256 nodes
#define NBLK 196        // edge blocks
#define EPB 16384       // edges per block

typedef unsigned short ushort_t;
using s16x8 = __attribute__((ext_vector_type(8))) short;
using us8   = __attribute__((ext_vector_type(8))) unsigned short;
using us4   = __attribute__((ext_vector_type(4))) unsigned short;
using f32x4 = __attribute__((ext_vector_type(4))) float;

__device__ __forceinline__ float bf2f(ushort_t u) {
    return __uint_as_float(((unsigned int)u) << 16);
}
__device__ __forceinline__ ushort_t f2bf(float f) {
    unsigned int x = __float_as_uint(f);
    unsigned int r = x + 0x7fffu + ((x >> 16) & 1u);
    return (ushort_t)(r >> 16);
}
__device__ __forceinline__ int clampi(int v, int hi) {
    return v < 0 ? 0 : (v >= hi ? hi - 1 : v);
}

// fp8 e4m3fn encode (RNE, saturate to 448) / decode
__device__ __forceinline__ unsigned char f2e4(float f) {
    unsigned char s = (unsigned char)((__float_as_uint(f) >> 31) << 7);
    float a = fabsf(f);
    if (a >= 0.015625f) {
        if (a > 448.f) a = 448.f;
        unsigned int u = __float_as_uint(a);
        u += 0x7FFFFu + ((u >> 20) & 1u);     // RNE into 3-bit mantissa
        int e8 = (int)(u >> 23) - 127 + 7;
        unsigned int m8 = (u >> 20) & 7u;
        if (e8 > 15) { e8 = 15; m8 = 6; }
        return s | (unsigned char)((e8 << 3) | m8);
    } else {
        int m = (int)rintf(a * 512.f);
        if (m > 7) return s | 0x08;
        return s | (unsigned char)m;
    }
}
__device__ __forceinline__ float e42f(unsigned int c) {
    unsigned int s = (c >> 7) & 1u;
    unsigned int e = (c >> 3) & 15u;
    unsigned int m = c & 7u;
    float v;
    if (e) v = __uint_as_float((s << 31) | ((e + 120u) << 23) | (m << 20));
    else { v = (float)(int)m * 0.001953125f; v = s ? -v : v; }
    return v;
}

// ---- workspace layout (bytes), total 32,627,072 (proven ws_size >= 39,272,064) ----
constexpr size_t OFF_GACC   = 0;          // 512*2*4 = 4096
constexpr size_t OFF_GCNT   = 4096;       // 512*4
constexpr size_t OFF_BASE   = 6144;       // (NB+1)*4 = 1568
constexpr size_t ZBYTES     = 8192;       // zeroed prefix
constexpr size_t OFF_COUNTS = 8192;       // u16 [NBLK][NB] = 153272 -> pad 161536
constexpr size_t OFF_SD     = 161536;     // packed (start<<10|deg) u32 [N] = 400000
constexpr size_t OFF_SRC    = 561536;     // int [E] = 12.8MB
constexpr size_t OFF_X8     = 13361536;   // fp8 [N,64] = 6.4MB
constexpr size_t OFF_EP     = 19761536;   // epairs int [E] = 12.8MB; agg bf16 [N,64] overlays
constexpr size_t OFF_WT     = 32561536;   // bf16 [256][128] = 65536 -> end 32,627,072

// P1: per-(block,bucket) edge counts via LDS histogram
__global__ __launch_bounds__(256) void k_count(const int* __restrict__ ei,
                                               ushort_t* __restrict__ counts) {
    __shared__ int h[NB];
    int blk = blockIdx.x, t = threadIdx.x;
    for (int i = t; i < NB; i += 256) h[i] = 0;
    __syncthreads();
    int e0 = blk * EPB;
    for (int i = 0; i < EPB; i += 256) {
        int e = e0 + i + t;
        if (e < N_EDGES) {
            int d = clampi(ei[N_EDGES + e], N_NODES);
            atomicAdd(&h[d >> 8], 1);
        }
    }
    __syncthreads();
    for (int i = t; i < NB; i += 256) counts[blk * NB + i] = (ushort_t)h[i];
}

// P2a: per-bucket column scan
__global__ __launch_bounds__(256) void k_scan_col(ushort_t* __restrict__ counts,
                                                  int* __restrict__ base) {
    __shared__ int a[256];
    __shared__ int orig[256];
    int b = blockIdx.x, t = threadIdx.x;
    int v = (t < NBLK) ? (int)counts[t * NB + b] : 0;
    orig[t] = v; a[t] = v;
    __syncthreads();
    for (int off = 1; off < 256; off <<= 1) {
        int u = (t >= off) ? a[t - off] : 0;
        __syncthreads();
        a[t] += u;
        __syncthreads();
    }
    if (t < NBLK) counts[t * NB + b] = (ushort_t)(a[t] - orig[t]);
    if (t == 255) base[b] = a[255];
}

// P2b: exclusive scan over bucket totals
__global__ __launch_bounds__(512) void k_scan_bucket(int* __restrict__ base) {
    __shared__ int a[512];
    __shared__ int orig[512];
    int t = threadIdx.x;
    int v = (t < NB) ? base[t] : 0;
    orig[t] = v; a[t] = v;
    __syncthreads();
    for (int off = 1; off < 512; off <<= 1) {
        int u = (t >= off) ? a[t - off] : 0;
        __syncthreads();
        a[t] += u;
        __syncthreads();
    }
    if (t < NB) base[t] = a[t] - orig[t];
    if (t == NB - 1) base[NB] = a[t];
}

// P3: scatter edges into bucket-contiguous runs; pack (src<<8)|dst_local
__global__ __launch_bounds__(256) void k_scatter(const int* __restrict__ ei,
                                                 const ushort_t* __restrict__ counts,
                                                 const int* __restrict__ base,
                                                 int* __restrict__ ep) {
    __shared__ int rnk[NB];
    __shared__ int ob[NB];
    int blk = blockIdx.x, t = threadIdx.x;
    for (int i = t; i < NB; i += 256) {
        rnk[i] = 0;
        ob[i] = base[i] + (int)counts[blk * NB + i];
    }
    __syncthreads();
    int e0 = blk * EPB;
    for (int i = 0; i < EPB; i += 256) {
        int e = e0 + i + t;
        if (e < N_EDGES) {
            int s = clampi(ei[e], N_NODES);
            int d = clampi(ei[N_EDGES + e], N_NODES);
            int b = d >> 8;
            int r = atomicAdd(&rnk[b], 1);
            ep[ob[b] + r] = (s << 8) | (d & 255);
        }
    }
}

// P4: per-bucket fine CSR; emit packed start|deg
__global__ __launch_bounds__(256) void k_csr(const int* __restrict__ ep,
                                             const int* __restrict__ base,
                                             int* __restrict__ srcs,
                                             unsigned int* __restrict__ sd) {
    __shared__ int ldeg[256];
    __shared__ int a[256];
    __shared__ int lcur[256];
    int b = blockIdx.x, t = threadIdx.x;
    int e0 = base[b], e1 = base[b + 1];
    ldeg[t] = 0;
    __syncthreads();
    for (int e = e0 + t; e < e1; e += 256) atomicAdd(&ldeg[ep[e] & 255], 1);
    __syncthreads();
    a[t] = ldeg[t];
    __syncthreads();
    for (int off = 1; off < 256; off <<= 1) {
        int u = (t >= off) ? a[t - off] : 0;
        __syncthreads();
        a[t] += u;
        __syncthreads();
    }
    int excl = a[t] - ldeg[t];
    lcur[t] = excl;
    __syncthreads();
    int n = (b << 8) + t;
    if (n < N_NODES) {
        int dgc = ldeg[t] < 1023 ? ldeg[t] : 1023;
        sd[n] = ((unsigned int)(e0 + excl) << 10) | (unsigned int)dgc;
    }
    for (int e = e0 + t; e < e1; e += 256) {
        int p = ep[e];
        int dl = p & 255;
        int r = atomicAdd(&lcur[dl], 1);
        srcs[e0 + r] = p >> 8;
    }
}

// K4: combined transposed bf16 weight WT[j][k]
__global__ void k_buildW(const float* __restrict__ Wl, const float* __restrict__ Wr,
                         ushort_t* __restrict__ WT) {
    int idx = blockIdx.x * blockDim.x + threadIdx.x;
    int j = idx >> 7;
    int k = idx & 127;
    ushort_t val = 0;
    if (k < IN_CH) val = f2bf(Wl[j * IN_CH + k]);
    else if (k >= 64 && k < 64 + IN_CH) val = f2bf(Wr[j * IN_CH + (k - 64)]);
    WT[idx] = val;
}

// K4b: x fp32 [N,50] -> x8 fp8 [N,64] (cols 50..63 = 0)
__global__ void k_conv8(const float* __restrict__ x, unsigned char* __restrict__ x8) {
    int t = blockIdx.x * blockDim.x + threadIdx.x;
    if (t < N_NODES * 64) {
        int n = t >> 6, c = t & 63;
        x8[t] = (c < IN_CH) ? f2e4(x[n * IN_CH + c]) : (unsigned char)0;
    }
}

// K5: wave-per-node gather mean from fp8 x8; quad-per-row, uchar4/lane, 4x MLP
__global__ void k_gather8(const unsigned char* __restrict__ x8, const int* __restrict__ batch,
                          const unsigned int* __restrict__ sd,
                          const int* __restrict__ srcs, ushort_t* __restrict__ agg,
                          int* __restrict__ gcnt) {
    int gid = (blockIdx.x * blockDim.x + threadIdx.x) >> 6;
    int lane = threadIdx.x & 63;
    if (gid >= N_NODES) return;
    int q = lane >> 4;
    int c16 = lane & 15;
    unsigned int v = sd[gid];
    int dg = (int)(v & 1023u);
    int st = (int)(v >> 10);
    float a0 = 0.f, a1 = 0.f, a2 = 0.f, a3 = 0.f;
    int i = 0;
    for (; i + 16 <= dg; i += 16) {
        int sA = srcs[st + i + q];
        int sB = srcs[st + i + 4 + q];
        int sC = srcs[st + i + 8 + q];
        int sD = srcs[st + i + 12 + q];
        uchar4 wA = *(const uchar4*)(x8 + (size_t)sA * 64 + (c16 << 2));
        uchar4 wB = *(const uchar4*)(x8 + (size_t)sB * 64 + (c16 << 2));
        uchar4 wC = *(const uchar4*)(x8 + (size_t)sC * 64 + (c16 << 2));
        uchar4 wD = *(const uchar4*)(x8 + (size_t)sD * 64 + (c16 << 2));
        a0 += e42f(wA.x) + e42f(wB.x) + e42f(wC.x) + e42f(wD.x);
        a1 += e42f(wA.y) + e42f(wB.y) + e42f(wC.y) + e42f(wD.y);
        a2 += e42f(wA.z) + e42f(wB.z) + e42f(wC.z) + e42f(wD.z);
        a3 += e42f(wA.w) + e42f(wB.w) + e42f(wC.w) + e42f(wD.w);
    }
    for (; i + 4 <= dg; i += 4) {
        int s = srcs[st + i + q];
        uchar4 w = *(const uchar4*)(x8 + (size_t)s * 64 + (c16 << 2));
        a0 += e42f(w.x); a1 += e42f(w.y); a2 += e42f(w.z); a3 += e42f(w.w);
    }
    int rem = dg - i;
    if (q < rem) {
        int s = srcs[st + i + q];
        uchar4 w = *(const uchar4*)(x8 + (size_t)s * 64 + (c16 << 2));
        a0 += e42f(w.x); a1 += e42f(w.y); a2 += e42f(w.z); a3 += e42f(w.w);
    }
    a0 += __shfl_xor(a0, 16); a1 += __shfl_xor(a1, 16);
    a2 += __shfl_xor(a2, 16); a3 += __shfl_xor(a3, 16);
    a0 += __shfl_xor(a0, 32); a1 += __shfl_xor(a1, 32);
    a2 += __shfl_xor(a2, 32); a3 += __shfl_xor(a3, 32);
    float inv = 1.0f / (float)(dg > 1 ? dg : 1);
    if (q == 0) {
        us4 o;
        o.x = f2bf(a0 * inv); o.y = f2bf(a1 * inv);
        o.z = f2bf(a2 * inv); o.w = f2bf(a3 * inv);
        *(us4*)(agg + (size_t)gid * 64 + (c16 << 2)) = o;
    }
    if (lane == 0) atomicAdd(&gcnt[clampi(batch[gid], N_GRAPHS)], 1);
}

// K6: fused MFMA GEMM [N,128]x[128,256] + bias + leaky_relu + W_c proj + graph-sum
// A K-layout: k in [0,50) = agg(bf16), [64,114) = x (scalar f2bf), else 0
__global__ __launch_bounds__(256) void k_gemm(const ushort_t* __restrict__ agg,
                                              const float* __restrict__ x,
                                              const ushort_t* __restrict__ WT,
                                              const float* __restrict__ bl,
                                              const float* __restrict__ Wc,
                                              const int* __restrict__ batch,
                                              float* __restrict__ gacc) {
    __shared__ ushort_t Alds[64 * 72];
    __shared__ ushort_t Blds[256 * 72];
    __shared__ float ypart[4][64][2];

    const int t = threadIdx.x;
    const int w = t >> 6;
    const int lane = t & 63;
    const int quad = lane >> 4;
    const int r16 = lane & 15;
    const int row0 = blockIdx.x * 64;

    f32x4 acc[4][4] = {};

    for (int kb = 0; kb < 128; kb += 64) {
        __syncthreads();
        {
            int row = t >> 2;
            int cc = (t & 3) << 4;
            int gr = row0 + row;
            ushort_t* dst = &Alds[row * 72 + cc];
            if (kb == 0) {
                if (gr < N_NODES) {
                    const us8* gp = (const us8*)(agg + (size_t)gr * 64 + cc);
                    *(us8*)(dst) = gp[0];
                    *(us8*)(dst + 8) = gp[1];
                } else {
#pragma unroll
                    for (int qq = 0; qq < 16; qq++) dst[qq] = 0;
                }
            } else {
#pragma unroll
                for (int qq = 0; qq < 16; qq++) {
                    int c = cc + qq;
                    ushort_t val = 0;
                    if (gr < N_NODES && c < IN_CH) val = f2bf(x[gr * IN_CH + c]);
                    dst[qq] = val;
                }
            }
        }
        {
            const us8* gp = (const us8*)(WT + t * 128 + kb);
#pragma unroll
            for (int i = 0; i < 8; i++)
                *(us8*)&Blds[t * 72 + i * 8] = gp[i];
        }
        __syncthreads();
#pragma unroll
        for (int ks = 0; ks < 64; ks += 32) {
            s16x8 af[4], bfr[4];
#pragma unroll
            for (int mi = 0; mi < 4; mi++)
                af[mi] = *(const s16x8*)&Alds[(16 * mi + r16) * 72 + ks + (quad << 3)];
#pragma unroll
            for (int ni = 0; ni < 4; ni++)
                bfr[ni] = *(const s16x8*)&Blds[(w * 64 + 16 * ni + r16) * 72 + ks + (quad << 3)];
#pragma unroll
            for (int mi = 0; mi < 4; mi++)
#pragma unroll
                for (int ni = 0; ni < 4; ni++)
                    acc[mi][ni] = __builtin_amdgcn_mfma_f32_16x16x32_bf16(
                        af[mi], bfr[ni], acc[mi][ni], 0, 0, 0);
        }
    }

    float blv[4], w0v[4], w1v[4];
#pragma unroll
    for (int ni = 0; ni < 4; ni++) {
        int col = w * 64 + 16 * ni + r16;
        blv[ni] = bl[col];
        w0v[ni] = Wc[col];
        w1v[ni] = Wc[HID + col];
    }
#pragma unroll
    for (int mi = 0; mi < 4; mi++) {
#pragma unroll
        for (int r = 0; r < 4; r++) {
            float p0 = 0.f, p1 = 0.f;
#pragma unroll
            for (int ni = 0; ni < 4; ni++) {
                float h = acc[mi][ni][r] + blv[ni];
                h = (h > 0.f) ? h : 0.01f * h;
                p0 = fmaf(h, w0v[ni], p0);
                p1 = fmaf(h, w1v[ni], p1);
            }
#pragma unroll
            for (int off = 1; off < 16; off <<= 1) {
                p0 += __shfl_xor(p0, off, 16);
                p1 += __shfl_xor(p1, off, 16);
            }
            if (r16 == 0) {
                int rl = 16 * mi + (quad << 2) + r;
                ypart[w][rl][0] = p0;
                ypart[w][rl][1] = p1;
            }
        }
    }
    __syncthreads();
    if (t < 128) {
        int rl = t >> 1, cc = t & 1;
        float s = ypart[0][rl][cc] + ypart[1][rl][cc] + ypart[2][rl][cc] + ypart[3][rl][cc];
        int node = row0 + rl;
        if (node < N_NODES) {
            int g = clampi(batch[node], N_GRAPHS);
            atomicAdd(&gacc[g * 2 + cc], s);
        }
    }
}

// K7: finalize
__global__ void k_fin(const float* __restrict__ gacc, const int* __restrict__ gcnt,
                      const float* __restrict__ bc, float* __restrict__ out) {
    int t = blockIdx.x * blockDim.x + threadIdx.x;
    if (t < N_GRAPHS * 2) {
        int g = t >> 1, c = t & 1;
        int cnt = gcnt[g];
        out[t] = gacc[t] / (float)(cnt > 1 ? cnt : 1) + bc[c];
    }
}

extern "C" void kernel_launch(void* const* d_in, const int* in_sizes, int n_in,
                              void* d_out, int out_size, void* d_ws, size_t ws_size,
                              hipStream_t stream) {
    const float* x  = (const float*)d_in[0];
    const int* ei   = (const int*)d_in[1];
    const int* batch= (const int*)d_in[2];
    const float* Wl = (const float*)d_in[3];
    const float* bl = (const float*)d_in[4];
    const float* Wr = (const float*)d_in[5];
    const float* Wc = (const float*)d_in[6];
    const float* bc = (const float*)d_in[7];
    float* out = (float*)d_out;

    char* ws = (char*)d_ws;
    float* gacc        = (float*)(ws + OFF_GACC);
    int* gcnt          = (int*)(ws + OFF_GCNT);
    int* base          = (int*)(ws + OFF_BASE);
    ushort_t* counts   = (ushort_t*)(ws + OFF_COUNTS);
    unsigned int* sd   = (unsigned int*)(ws + OFF_SD);
    int* srcs          = (int*)(ws + OFF_SRC);
    unsigned char* x8  = (unsigned char*)(ws + OFF_X8);
    int* ep            = (int*)(ws + OFF_EP);
    ushort_t* agg      = (ushort_t*)(ws + OFF_EP);   // overlays dead ep
    ushort_t* WT       = (ushort_t*)(ws + OFF_WT);

    hipMemsetAsync(ws, 0, ZBYTES, stream);
    k_count      <<<NBLK, 256, 0, stream>>>(ei, counts);
    k_scan_col   <<<NB, 256, 0, stream>>>(counts, base);
    k_scan_bucket<<<1, 512, 0, stream>>>(base);
    k_scatter    <<<NBLK, 256, 0, stream>>>(ei, counts, base, ep);
    k_csr        <<<NB, 256, 0, stream>>>(ep, base, srcs, sd);
    k_buildW     <<<(HID * 128) / 256, 256, 0, stream>>>(Wl, Wr, WT);
    k_conv8      <<<(N_NODES * 64 + 255) / 256, 256, 0, stream>>>(x, x8);
    k_gather8    <<<(N_NODES + 3) / 4, 256, 0, stream>>>(x8, batch, sd, srcs, agg, gcnt);
    k_gemm       <<<(N_NODES + 63) / 64, 256, 0, stream>>>(agg, x, WT, bl, Wc, batch, gacc);
    k_fin        <<<4, 256, 0, stream>>>(gacc, gcnt, bc, out);
}

// Round 7
// 466.201 us; speedup vs baseline: 1.1277x; 1.1277x over previous
//
#include <hip/hip_runtime.h>

#define N_NODES 100000
#define N_EDGES 3200000
#define N_GRAPHS 512
#define IN_CH 50
#define HID 256
#define NB 391          // buckets of 256 nodes
#define NBLK 196        // edge blocks
#define EPB 16384       // edges per block

typedef unsigned short ushort_t;
using s16x8 = __attribute__((ext_vector_type(8))) short;
using us8   = __attribute__((ext_vector_type(8))) unsigned short;
using us4   = __attribute__((ext_vector_type(4))) unsigned short;
using f32x4 = __attribute__((ext_vector_type(4))) float;

__device__ __forceinline__ float bf2f(ushort_t u) {
    return __uint_as_float(((unsigned int)u) << 16);
}
__device__ __forceinline__ ushort_t f2bf(float f) {
    unsigned int x = __float_as_uint(f);
    unsigned int r = x + 0x7fffu + ((x >> 16) & 1u);
    return (ushort_t)(r >> 16);
}
__device__ __forceinline__ int clampi(int v, int hi) {
    return v < 0 ? 0 : (v >= hi ? hi - 1 : v);
}

// fp8 e4m3fn encode (RNE, saturate to 448) / decode
__device__ __forceinline__ unsigned char f2e4(float f) {
    unsigned char s = (unsigned char)((__float_as_uint(f) >> 31) << 7);
    float a = fabsf(f);
    if (a >= 0.015625f) {
        if (a > 448.f) a = 448.f;
        unsigned int u = __float_as_uint(a);
        u += 0x7FFFFu + ((u >> 20) & 1u);     // RNE into 3-bit mantissa
        int e8 = (int)(u >> 23) - 127 + 7;
        unsigned int m8 = (u >> 20) & 7u;
        if (e8 > 15) { e8 = 15; m8 = 6; }
        return s | (unsigned char)((e8 << 3) | m8);
    } else {
        int m = (int)rintf(a * 512.f);
        if (m > 7) return s | 0x08;
        return s | (unsigned char)m;
    }
}
// branchless e4m3 -> f32: exact for normals AND denormals (bit-place + 2^120 scale)
__device__ __forceinline__ float e42f(unsigned int c) {
    unsigned int w = ((c & 0x80u) << 24) | ((c & 0x7fu) << 20);
    return __uint_as_float(w) * 0x1p120f;
}

// ---- workspace layout (bytes), total 32,627,072 (proven ws_size >= 39,272,064) ----
constexpr size_t OFF_GACC   = 0;          // 512*2*4 = 4096
constexpr size_t OFF_GCNT   = 4096;       // 512*4
constexpr size_t OFF_BASE   = 6144;       // (NB+1)*4 = 1568
constexpr size_t ZBYTES     = 8192;       // zeroed prefix
constexpr size_t OFF_COUNTS = 8192;       // u16 [NBLK][NB] = 153272 -> pad 161536
constexpr size_t OFF_SD     = 161536;     // packed (start<<10|deg) u32 [N] = 400000
constexpr size_t OFF_SRC    = 561536;     // int [E] = 12.8MB
constexpr size_t OFF_X8     = 13361536;   // fp8 [N,64] = 6.4MB
constexpr size_t OFF_EP     = 19761536;   // epairs int [E] = 12.8MB; agg bf16 [N,64] overlays
constexpr size_t OFF_WT     = 32561536;   // bf16 [256][128] = 65536 -> end 32,627,072

// P1: per-(block,bucket) edge counts via LDS histogram
__global__ __launch_bounds__(256) void k_count(const int* __restrict__ ei,
                                               ushort_t* __restrict__ counts) {
    __shared__ int h[NB];
    int blk = blockIdx.x, t = threadIdx.x;
    for (int i = t; i < NB; i += 256) h[i] = 0;
    __syncthreads();
    int e0 = blk * EPB;
    for (int i = 0; i < EPB; i += 256) {
        int e = e0 + i + t;
        if (e < N_EDGES) {
            int d = clampi(ei[N_EDGES + e], N_NODES);
            atomicAdd(&h[d >> 8], 1);
        }
    }
    __syncthreads();
    for (int i = t; i < NB; i += 256) counts[blk * NB + i] = (ushort_t)h[i];
}

// P2a: per-bucket column scan
__global__ __launch_bounds__(256) void k_scan_col(ushort_t* __restrict__ counts,
                                                  int* __restrict__ base) {
    __shared__ int a[256];
    __shared__ int orig[256];
    int b = blockIdx.x, t = threadIdx.x;
    int v = (t < NBLK) ? (int)counts[t * NB + b] : 0;
    orig[t] = v; a[t] = v;
    __syncthreads();
    for (int off = 1; off < 256; off <<= 1) {
        int u = (t >= off) ? a[t - off] : 0;
        __syncthreads();
        a[t] += u;
        __syncthreads();
    }
    if (t < NBLK) counts[t * NB + b] = (ushort_t)(a[t] - orig[t]);
    if (t == 255) base[b] = a[255];
}

// P2b: exclusive scan over bucket totals
__global__ __launch_bounds__(512) void k_scan_bucket(int* __restrict__ base) {
    __shared__ int a[512];
    __shared__ int orig[512];
    int t = threadIdx.x;
    int v = (t < NB) ? base[t] : 0;
    orig[t] = v; a[t] = v;
    __syncthreads();
    for (int off = 1; off < 512; off <<= 1) {
        int u = (t >= off) ? a[t - off] : 0;
        __syncthreads();
        a[t] += u;
        __syncthreads();
    }
    if (t < NB) base[t] = a[t] - orig[t];
    if (t == NB - 1) base[NB] = a[t];
}

// P3: scatter edges into bucket-contiguous runs; pack (src<<8)|dst_local
__global__ __launch_bounds__(256) void k_scatter(const int* __restrict__ ei,
                                                 const ushort_t* __restrict__ counts,
                                                 const int* __restrict__ base,
                                                 int* __restrict__ ep) {
    __shared__ int rnk[NB];
    __shared__ int ob[NB];
    int blk = blockIdx.x, t = threadIdx.x;
    for (int i = t; i < NB; i += 256) {
        rnk[i] = 0;
        ob[i] = base[i] + (int)counts[blk * NB + i];
    }
    __syncthreads();
    int e0 = blk * EPB;
    for (int i = 0; i < EPB; i += 256) {
        int e = e0 + i + t;
        if (e < N_EDGES) {
            int s = clampi(ei[e], N_NODES);
            int d = clampi(ei[N_EDGES + e], N_NODES);
            int b = d >> 8;
            int r = atomicAdd(&rnk[b], 1);
            ep[ob[b] + r] = (s << 8) | (d & 255);
        }
    }
}

// P4: per-bucket fine CSR; emit packed start|deg
__global__ __launch_bounds__(256) void k_csr(const int* __restrict__ ep,
                                             const int* __restrict__ base,
                                             int* __restrict__ srcs,
                                             unsigned int* __restrict__ sd) {
    __shared__ int ldeg[256];
    __shared__ int a[256];
    __shared__ int lcur[256];
    int b = blockIdx.x, t = threadIdx.x;
    int e0 = base[b], e1 = base[b + 1];
    ldeg[t] = 0;
    __syncthreads();
    for (int e = e0 + t; e < e1; e += 256) atomicAdd(&ldeg[ep[e] & 255], 1);
    __syncthreads();
    a[t] = ldeg[t];
    __syncthreads();
    for (int off = 1; off < 256; off <<= 1) {
        int u = (t >= off) ? a[t - off] : 0;
        __syncthreads();
        a[t] += u;
        __syncthreads();
    }
    int excl = a[t] - ldeg[t];
    lcur[t] = excl;
    __syncthreads();
    int n = (b << 8) + t;
    if (n < N_NODES) {
        int dgc = ldeg[t] < 1023 ? ldeg[t] : 1023;
        sd[n] = ((unsigned int)(e0 + excl) << 10) | (unsigned int)dgc;
    }
    for (int e = e0 + t; e < e1; e += 256) {
        int p = ep[e];
        int dl = p & 255;
        int r = atomicAdd(&lcur[dl], 1);
        srcs[e0 + r] = p >> 8;
    }
}

// K4: combined transposed bf16 weight WT[j][k]
__global__ void k_buildW(const float* __restrict__ Wl, const float* __restrict__ Wr,
                         ushort_t* __restrict__ WT) {
    int idx = blockIdx.x * blockDim.x + threadIdx.x;
    int j = idx >> 7;
    int k = idx & 127;
    ushort_t val = 0;
    if (k < IN_CH) val = f2bf(Wl[j * IN_CH + k]);
    else if (k >= 64 && k < 64 + IN_CH) val = f2bf(Wr[j * IN_CH + (k - 64)]);
    WT[idx] = val;
}

// K4b: x fp32 [N,50] -> x8 fp8 [N,64] (cols 50..63 = 0)
__global__ void k_conv8(const float* __restrict__ x, unsigned char* __restrict__ x8) {
    int t = blockIdx.x * blockDim.x + threadIdx.x;
    if (t < N_NODES * 64) {
        int n = t >> 6, c = t & 63;
        x8[t] = (c < IN_CH) ? f2e4(x[n * IN_CH + c]) : (unsigned char)0;
    }
}

// K5: wave-per-node gather mean from fp8 x8; quad-per-row, uchar4/lane, 4x MLP
__global__ void k_gather8(const unsigned char* __restrict__ x8, const int* __restrict__ batch,
                          const unsigned int* __restrict__ sd,
                          const int* __restrict__ srcs, ushort_t* __restrict__ agg,
                          int* __restrict__ gcnt) {
    int gid = (blockIdx.x * blockDim.x + threadIdx.x) >> 6;
    int lane = threadIdx.x & 63;
    if (gid >= N_NODES) return;
    int q = lane >> 4;
    int c16 = lane & 15;
    unsigned int v = sd[gid];
    int dg = (int)(v & 1023u);
    int st = (int)(v >> 10);
    float a0 = 0.f, a1 = 0.f, a2 = 0.f, a3 = 0.f;
    int i = 0;
    for (; i + 16 <= dg; i += 16) {
        int sA = srcs[st + i + q];
        int sB = srcs[st + i + 4 + q];
        int sC = srcs[st + i + 8 + q];
        int sD = srcs[st + i + 12 + q];
        uchar4 wA = *(const uchar4*)(x8 + (size_t)sA * 64 + (c16 << 2));
        uchar4 wB = *(const uchar4*)(x8 + (size_t)sB * 64 + (c16 << 2));
        uchar4 wC = *(const uchar4*)(x8 + (size_t)sC * 64 + (c16 << 2));
        uchar4 wD = *(const uchar4*)(x8 + (size_t)sD * 64 + (c16 << 2));
        a0 += e42f(wA.x) + e42f(wB.x) + e42f(wC.x) + e42f(wD.x);
        a1 += e42f(wA.y) + e42f(wB.y) + e42f(wC.y) + e42f(wD.y);
        a2 += e42f(wA.z) + e42f(wB.z) + e42f(wC.z) + e42f(wD.z);
        a3 += e42f(wA.w) + e42f(wB.w) + e42f(wC.w) + e42f(wD.w);
    }
    for (; i + 4 <= dg; i += 4) {
        int s = srcs[st + i + q];
        uchar4 w = *(const uchar4*)(x8 + (size_t)s * 64 + (c16 << 2));
        a0 += e42f(w.x); a1 += e42f(w.y); a2 += e42f(w.z); a3 += e42f(w.w);
    }
    int rem = dg - i;
    if (q < rem) {
        int s = srcs[st + i + q];
        uchar4 w = *(const uchar4*)(x8 + (size_t)s * 64 + (c16 << 2));
        a0 += e42f(w.x); a1 += e42f(w.y); a2 += e42f(w.z); a3 += e42f(w.w);
    }
    a0 += __shfl_xor(a0, 16); a1 += __shfl_xor(a1, 16);
    a2 += __shfl_xor(a2, 16); a3 += __shfl_xor(a3, 16);
    a0 += __shfl_xor(a0, 32); a1 += __shfl_xor(a1, 32);
    a2 += __shfl_xor(a2, 32); a3 += __shfl_xor(a3, 32);
    float inv = 1.0f / (float)(dg > 1 ? dg : 1);
    if (q == 0) {
        us4 o;
        o.x = f2bf(a0 * inv); o.y = f2bf(a1 * inv);
        o.z = f2bf(a2 * inv); o.w = f2bf(a3 * inv);
        *(us4*)(agg + (size_t)gid * 64 + (c16 << 2)) = o;
    }
    if (lane == 0) atomicAdd(&gcnt[clampi(batch[gid], N_GRAPHS)], 1);
}

// K6: fused MFMA GEMM [N,128]x[128,256] + bias + leaky_relu + W_c proj + graph-sum
// A K-layout: k in [0,50) = agg(bf16), [64,114) = x (scalar f2bf), else 0
__global__ __launch_bounds__(256) void k_gemm(const ushort_t* __restrict__ agg,
                                              const float* __restrict__ x,
                                              const ushort_t* __restrict__ WT,
                                              const float* __restrict__ bl,
                                              const float* __restrict__ Wc,
                                              const int* __restrict__ batch,
                                              float* __restrict__ gacc) {
    __shared__ ushort_t Alds[64 * 72];
    __shared__ ushort_t Blds[256 * 72];
    __shared__ float ypart[4][64][2];

    const int t = threadIdx.x;
    const int w = t >> 6;
    const int lane = t & 63;
    const int quad = lane >> 4;
    const int r16 = lane & 15;
    const int row0 = blockIdx.x * 64;

    f32x4 acc[4][4] = {};

    for (int kb = 0; kb < 128; kb += 64) {
        __syncthreads();
        {
            int row = t >> 2;
            int cc = (t & 3) << 4;
            int gr = row0 + row;
            ushort_t* dst = &Alds[row * 72 + cc];
            if (kb == 0) {
                if (gr < N_NODES) {
                    const us8* gp = (const us8*)(agg + (size_t)gr * 64 + cc);
                    *(us8*)(dst) = gp[0];
                    *(us8*)(dst + 8) = gp[1];
                } else {
#pragma unroll
                    for (int qq = 0; qq < 16; qq++) dst[qq] = 0;
                }
            } else {
#pragma unroll
                for (int qq = 0; qq < 16; qq++) {
                    int c = cc + qq;
                    ushort_t val = 0;
                    if (gr < N_NODES && c < IN_CH) val = f2bf(x[gr * IN_CH + c]);
                    dst[qq] = val;
                }
            }
        }
        {
            const us8* gp = (const us8*)(WT + t * 128 + kb);
#pragma unroll
            for (int i = 0; i < 8; i++)
                *(us8*)&Blds[t * 72 + i * 8] = gp[i];
        }
        __syncthreads();
#pragma unroll
        for (int ks = 0; ks < 64; ks += 32) {
            s16x8 af[4], bfr[4];
#pragma unroll
            for (int mi = 0; mi < 4; mi++)
                af[mi] = *(const s16x8*)&Alds[(16 * mi + r16) * 72 + ks + (quad << 3)];
#pragma unroll
            for (int ni = 0; ni < 4; ni++)
                bfr[ni] = *(const s16x8*)&Blds[(w * 64 + 16 * ni + r16) * 72 + ks + (quad << 3)];
#pragma unroll
            for (int mi = 0; mi < 4; mi++)
#pragma unroll
                for (int ni = 0; ni < 4; ni++)
                    acc[mi][ni] = __builtin_amdgcn_mfma_f32_16x16x32_bf16(
                        af[mi], bfr[ni], acc[mi][ni], 0, 0, 0);
        }
    }

    float blv[4], w0v[4], w1v[4];
#pragma unroll
    for (int ni = 0; ni < 4; ni++) {
        int col = w * 64 + 16 * ni + r16;
        blv[ni] = bl[col];
        w0v[ni] = Wc[col];
        w1v[ni] = Wc[HID + col];
    }
#pragma unroll
    for (int mi = 0; mi < 4; mi++) {
#pragma unroll
        for (int r = 0; r < 4; r++) {
            float p0 = 0.f, p1 = 0.f;
#pragma unroll
            for (int ni = 0; ni < 4; ni++) {
                float h = acc[mi][ni][r] + blv[ni];
                h = (h > 0.f) ? h : 0.01f * h;
                p0 = fmaf(h, w0v[ni], p0);
                p1 = fmaf(h, w1v[ni], p1);
            }
#pragma unroll
            for (int off = 1; off < 16; off <<= 1) {
                p0 += __shfl_xor(p0, off, 16);
                p1 += __shfl_xor(p1, off, 16);
            }
            if (r16 == 0) {
                int rl = 16 * mi + (quad << 2) + r;
                ypart[w][rl][0] = p0;
                ypart[w][rl][1] = p1;
            }
        }
    }
    __syncthreads();
    if (t < 128) {
        int rl = t >> 1, cc = t & 1;
        float s = ypart[0][rl][cc] + ypart[1][rl][cc] + ypart[2][rl][cc] + ypart[3][rl][cc];
        int node = row0 + rl;
        if (node < N_NODES) {
            int g = clampi(batch[node], N_GRAPHS);
            atomicAdd(&gacc[g * 2 + cc], s);
        }
    }
}

// K7: finalize
__global__ void k_fin(const float* __restrict__ gacc, const int* __restrict__ gcnt,
                      const float* __restrict__ bc, float* __restrict__ out) {
    int t = blockIdx.x * blockDim.x + threadIdx.x;
    if (t < N_GRAPHS * 2) {
        int g = t >> 1, c = t & 1;
        int cnt = gcnt[g];
        out[t] = gacc[t] / (float)(cnt > 1 ? cnt : 1) + bc[c];
    }
}

extern "C" void kernel_launch(void* const* d_in, const int* in_sizes, int n_in,
                              void* d_out, int out_size, void* d_ws, size_t ws_size,
                              hipStream_t stream) {
    const float* x  = (const float*)d_in[0];
    const int* ei   = (const int*)d_in[1];
    const int* batch= (const int*)d_in[2];
    const float* Wl = (const float*)d_in[3];
    const float* bl = (const float*)d_in[4];
    const float* Wr = (const float*)d_in[5];
    const float* Wc = (const float*)d_in[6];
    const float* bc = (const float*)d_in[7];
    float* out = (float*)d_out;

    char* ws = (char*)d_ws;
    float* gacc        = (float*)(ws + OFF_GACC);
    int* gcnt          = (int*)(ws + OFF_GCNT);
    int* base          = (int*)(ws + OFF_BASE);
    ushort_t* counts   = (ushort_t*)(ws + OFF_COUNTS);
    unsigned int* sd   = (unsigned int*)(ws + OFF_SD);
    int* srcs          = (int*)(ws + OFF_SRC);
    unsigned char* x8  = (unsigned char*)(ws + OFF_X8);
    int* ep            = (int*)(ws + OFF_EP);
    ushort_t* agg      = (ushort_t*)(ws + OFF_EP);   // overlays dead ep
    ushort_t* WT       = (ushort_t*)(ws + OFF_WT);

    hipMemsetAsync(ws, 0, ZBYTES, stream);
    k_count      <<<NBLK, 256, 0, stream>>>(ei, counts);
    k_scan_col   <<<NB, 256, 0, stream>>>(counts, base);
    k_scan_bucket<<<1, 512, 0, stream>>>(base);
    k_scatter    <<<NBLK, 256, 0, stream>>>(ei, counts, base, ep);
    k_csr        <<<NB, 256, 0, stream>>>(ep, base, srcs, sd);
    k_buildW     <<<(HID * 128) / 256, 256, 0, stream>>>(Wl, Wr, WT);
    k_conv8      <<<(N_NODES * 64 + 255) / 256, 256, 0, stream>>>(x, x8);
    k_gather8    <<<(N_NODES + 3) / 4, 256, 0, stream>>>(x8, batch, sd, srcs, agg, gcnt);
    k_gemm       <<<(N_NODES + 63) / 64, 256, 0, stream>>>(agg, x, WT, bl, Wc, batch, gacc);
    k_fin        <<<4, 256, 0, stream>>>(gacc, gcnt, bc, out);
}